// Round 4
// baseline (153.856 us; speedup 1.0000x reference)
//
#include <hip/hip_runtime.h>
#include <hip/hip_bf16.h>
#include <stdint.h>

// ---------------------------------------------------------------------------
// MMD loss, N=4096 source + 4096 target rows, D=256, fp32 in, fp32 scalar out.
//
//   loss = (1/ns^2) * sum_ij s_i s_j K(i,j),  s_i = +1 (source) / -1 (target)
//   K(i,j) = sum_{k=0..4} exp(-l2_ij / (bw0 * 2^k)),  l2 = |xi|^2+|xj|^2-2<xi,xj>
//   bw0 = [2n*sum|x|^2 - 2*|colsum|^2] / (n^2-n) / 4      (closed form, no Gram)
//
// Pipeline (all deterministic, no atomics):
//   k1: fp32->bf16 cast to ws, per-row |x|^2, per-block colsum/sqsum partials
//   k2: bandwidth scalar from partials
//   k3: triangular-tiled bf16 MFMA Gram + fused exp epilogue -> per-block partial
//       *** v2: NO LDS, NO BARRIERS. tbf is 4 MB and L2-resident (fits each
//       XCD's 4 MB L2); fragments are loaded straight from global with a
//       2-step software pipeline. The previous LDS-staged version spent most
//       of its time in per-kt vmcnt(0)+barrier drains (guide: common mistake
//       #7 — don't stage what L2 already holds).
//       v2.1: s_setprio(1) around the MFMA cluster — waves here are
//       barrier-free/independent (the m191 attn regime where setprio is +4-7%,
//       not the m190 lockstep-GEMM regime where it is null).
//       [Rounds 0-3: GPUAcquisitionTimeout x4 — never executed. Resubmitting
//       unchanged; fragment indexing is byte-identical to the measured 108 µs
//       LDS kernel, so correctness is preserved by construction.] ***
//   k4: reduce 2080 partials -> loss
// ws usage ~4.5 MB.
// ---------------------------------------------------------------------------

#define NROW 8192
#define NS   4096
#define DD   256
#define TILE 128
#define NTB  64                     // 8192/128 row tiles
#define NBLK (NTB*(NTB+1)/2)        // 2080 triangular blocks
#define K1B  128                    // k1 blocks (64 rows each)

typedef __bf16 bf16_t;
typedef __bf16 bf16x8 __attribute__((ext_vector_type(8)));
typedef __bf16 bf16x4 __attribute__((ext_vector_type(4)));
typedef float  f32x4  __attribute__((ext_vector_type(4)));

// ws byte offsets
#define OFF_CPAR 0                          // float[4]
#define OFF_SQ   1024                       // float[8192]
#define OFF_CS   (OFF_SQ + 8192*4)          // float[K1B*256]
#define OFF_SS   (OFF_CS + K1B*256*4)       // float[K1B]
#define OFF_PART (OFF_SS + 1024)            // float[NBLK]
#define OFF_TBF  (1<<18)                    // bf16[8192*256] = 4 MB

// --------------------------- k1: prep ---------------------------------------
__global__ __launch_bounds__(256) void k1_prep(const float* __restrict__ src,
                                               const float* __restrict__ tgt,
                                               float* __restrict__ sq,
                                               float* __restrict__ cs_part,
                                               float* __restrict__ ss_part,
                                               bf16_t* __restrict__ tbf) {
  const int b = blockIdx.x, tid = threadIdx.x;
  const int w = tid >> 6, lane = tid & 63;
  float4 csum = make_float4(0.f, 0.f, 0.f, 0.f);
  float wss = 0.f;
  for (int r = 0; r < 16; ++r) {
    const int row = b * 64 + w * 16 + r;
    const float* rp = (row < NS) ? (src + (size_t)row * DD)
                                 : (tgt + (size_t)(row - NS) * DD);
    float4 v = ((const float4*)rp)[lane];
    bf16x4 o;
    o[0] = (bf16_t)v.x; o[1] = (bf16_t)v.y; o[2] = (bf16_t)v.z; o[3] = (bf16_t)v.w;
    *(bf16x4*)(tbf + (size_t)row * DD + lane * 4) = o;
    float s2 = v.x*v.x + v.y*v.y + v.z*v.z + v.w*v.w;
    #pragma unroll
    for (int off = 32; off >= 1; off >>= 1) s2 += __shfl_xor(s2, off);
    if (lane == 0) { sq[row] = s2; wss += s2; }
    csum.x += v.x; csum.y += v.y; csum.z += v.z; csum.w += v.w;
  }
  __shared__ float cls[4][256];
  __shared__ float sls[4];
  ((float4*)cls[w])[lane] = csum;
  if (lane == 0) sls[w] = wss;
  __syncthreads();
  cs_part[b * 256 + tid] = cls[0][tid] + cls[1][tid] + cls[2][tid] + cls[3][tid];
  if (tid == 0) ss_part[b] = sls[0] + sls[1] + sls[2] + sls[3];
}

// --------------------------- k2: bandwidth -----------------------------------
__global__ __launch_bounds__(256) void k2_bw(const float* __restrict__ cs_part,
                                             const float* __restrict__ ss_part,
                                             float* __restrict__ cpar) {
  const int tid = threadIdx.x, w = tid >> 6, lane = tid & 63;
  float c = 0.f;
  for (int b = 0; b < K1B; ++b) c += cs_part[b * 256 + tid];
  double csq = (double)c * (double)c;
  double ssq = (tid < K1B) ? (double)ss_part[tid] : 0.0;
  #pragma unroll
  for (int off = 32; off >= 1; off >>= 1) {
    csq += __shfl_xor(csq, off);
    ssq += __shfl_xor(ssq, off);
  }
  __shared__ double rc[4], rs[4];
  if (lane == 0) { rc[w] = csq; rs[w] = ssq; }
  __syncthreads();
  if (tid == 0) {
    double C = rc[0] + rc[1] + rc[2] + rc[3];
    double S = rs[0] + rs[1] + rs[2] + rs[3];
    const double n = (double)NROW;
    double suml2 = 2.0 * n * S - 2.0 * C;
    double bw0 = suml2 / (n * n - n) / 4.0;   // / KERNEL_MUL^(KERNEL_NUM//2)
    // v = exp2(-l2 * cE) = exp(-l2/(16*bw0)); kernels = v+v^2+v^4+v^8+v^16
    cpar[0] = (float)(1.4426950408889634 / (16.0 * bw0));
  }
}

// --------------------------- k3: Gram + fused epilogue -----------------------
// Barrier-free: each wave computes a 64x64 quadrant of a 128x128 tile pair,
// loading MFMA fragments directly from global (L2-hot, 4 MB total working set).
// Fragment load pattern: 16 rows x 64 contiguous B = 16 fully-used 64B lines.

__device__ __forceinline__ void ldfrag(bf16x8 a[4], bf16x8 b[4],
                                       const bf16_t* __restrict__ Ab,
                                       const bf16_t* __restrict__ Bb,
                                       int ks) {
  #pragma unroll
  for (int i = 0; i < 4; ++i) {
    a[i] = *(const bf16x8*)(Ab + (size_t)i * 16 * DD + ks * 32);
    b[i] = *(const bf16x8*)(Bb + (size_t)i * 16 * DD + ks * 32);
  }
}

__device__ __forceinline__ void domfma(f32x4 acc[4][4],
                                       const bf16x8 a[4], const bf16x8 b[4]) {
  __builtin_amdgcn_s_setprio(1);
  #pragma unroll
  for (int mi = 0; mi < 4; ++mi)
    #pragma unroll
    for (int ni = 0; ni < 4; ++ni)
      acc[mi][ni] = __builtin_amdgcn_mfma_f32_16x16x32_bf16(
          a[mi], b[ni], acc[mi][ni], 0, 0, 0);
  __builtin_amdgcn_s_setprio(0);
}

__global__ __launch_bounds__(256) void k3_mmd(const bf16_t* __restrict__ tbf,
                                              const float* __restrict__ sqg,
                                              const float* __restrict__ cpar,
                                              float* __restrict__ part) {
  __shared__ float red[4];

  const int t = blockIdx.x;
  int bi = (int)((sqrtf(8.0f * (float)t + 1.0f) - 1.0f) * 0.5f);
  while ((bi + 1) * (bi + 2) / 2 <= t) ++bi;
  while (bi * (bi + 1) / 2 > t) --bi;
  const int bj = t - bi * (bi + 1) / 2;            // bj <= bi

  const int tid = threadIdx.x;
  const int w = tid >> 6, lane = tid & 63;
  const int m0 = (w >> 1) * 64, n0 = (w & 1) * 64; // wave quadrant in 128x128

  const float cE = cpar[0];

  f32x4 acc[4][4] = {};

  // Per-lane fragment base pointers. Row = tile_base + quadrant + frag row
  // (lane&15); k-offset within a 32-wide k-step = (lane>>4)*8 elements.
  const bf16_t* Ag = tbf + (size_t)(bi * TILE + m0 + (lane & 15)) * DD +
                     (lane >> 4) * 8;
  const bf16_t* Bg = tbf + (size_t)(bj * TILE + n0 + (lane & 15)) * DD +
                     (lane >> 4) * 8;

  // K = 256 in 8 k-steps of 32, 2-deep software pipeline (static buffers —
  // runtime-indexed ext_vector arrays would spill to scratch).
  bf16x8 a0[4], b0[4], a1[4], b1[4];
  ldfrag(a0, b0, Ag, Bg, 0);
  ldfrag(a1, b1, Ag, Bg, 1);
  #pragma unroll
  for (int ks = 0; ks < 8; ks += 2) {
    domfma(acc, a0, b0);
    if (ks + 2 < 8) ldfrag(a0, b0, Ag, Bg, ks + 2);
    domfma(acc, a1, b1);
    if (ks + 3 < 8) ldfrag(a1, b1, Ag, Bg, ks + 3);
  }

  // Fused epilogue: e = (2g - sqi - sqj)*cE; v = 2^e; K = v+v^2+v^4+v^8+v^16
  const float c2 = 2.0f * cE;
  float bjv[4];
  #pragma unroll
  for (int ni = 0; ni < 4; ++ni)
    bjv[ni] = sqg[bj * TILE + n0 + ni * 16 + (lane & 15)] * cE;

  float tsum = 0.f;
  #pragma unroll
  for (int mi = 0; mi < 4; ++mi) {
    float ai[4];
    #pragma unroll
    for (int r = 0; r < 4; ++r)
      ai[r] = sqg[bi * TILE + m0 + mi * 16 + (lane >> 4) * 4 + r] * cE;
    #pragma unroll
    for (int ni = 0; ni < 4; ++ni) {
      #pragma unroll
      for (int r = 0; r < 4; ++r) {
        const float g = acc[mi][ni][r];
        const float e = fmaf(g, c2, -(ai[r] + bjv[ni]));
        const float v   = __builtin_amdgcn_exp2f(e);
        const float v2  = v * v;
        const float v4  = v2 * v2;
        const float v8  = v4 * v4;
        const float v16 = v8 * v8;
        tsum += v + v2 + v4 + v8 + v16;
      }
    }
  }
  #pragma unroll
  for (int off = 32; off >= 1; off >>= 1) tsum += __shfl_xor(tsum, off);
  if (lane == 0) red[w] = tsum;
  __syncthreads();
  if (tid == 0) {
    const float s    = red[0] + red[1] + red[2] + red[3];
    const float sign = ((bi < NS / TILE) == (bj < NS / TILE)) ? 1.f : -1.f;
    const float wt   = (bi == bj) ? 1.f : 2.f;     // off-diag tiles counted twice
    part[t] = s * sign * wt;
  }
}

// --------------------------- k4: finalize ------------------------------------
__global__ __launch_bounds__(256) void k4_fin(const float* __restrict__ part,
                                              float* __restrict__ out) {
  const int tid = threadIdx.x, w = tid >> 6, lane = tid & 63;
  double s = 0.0;
  for (int i = tid; i < NBLK; i += 256) s += (double)part[i];
  #pragma unroll
  for (int off = 32; off >= 1; off >>= 1) s += __shfl_xor(s, off);
  __shared__ double rd[4];
  if (lane == 0) rd[w] = s;
  __syncthreads();
  if (tid == 0)
    out[0] = (float)((rd[0] + rd[1] + rd[2] + rd[3]) /
                     ((double)NS * (double)NS));
}

// --------------------------- launch ------------------------------------------
extern "C" void kernel_launch(void* const* d_in, const int* in_sizes, int n_in,
                              void* d_out, int out_size, void* d_ws, size_t ws_size,
                              hipStream_t stream) {
  const float* src = (const float*)d_in[0];
  const float* tgt = (const float*)d_in[1];
  char* ws = (char*)d_ws;
  float*  cpar = (float*)(ws + OFF_CPAR);
  float*  sq   = (float*)(ws + OFF_SQ);
  float*  csp  = (float*)(ws + OFF_CS);
  float*  ssp  = (float*)(ws + OFF_SS);
  float*  part = (float*)(ws + OFF_PART);
  bf16_t* tbf  = (bf16_t*)(ws + OFF_TBF);

  k1_prep<<<K1B, 256, 0, stream>>>(src, tgt, sq, csp, ssp, tbf);
  k2_bw  <<<1,   256, 0, stream>>>(csp, ssp, cpar);
  k3_mmd <<<NBLK,256, 0, stream>>>(tbf, sq, cpar, part);
  k4_fin <<<1,   256, 0, stream>>>(part, (float*)d_out);
}

// Round 7
// 109.390 us; speedup vs baseline: 1.4065x; 1.4065x over previous
//
#include <hip/hip_runtime.h>
#include <hip/hip_bf16.h>
#include <stdint.h>

// ---------------------------------------------------------------------------
// MMD loss, N=4096 source + 4096 target rows, D=256, fp32 in, fp32 scalar out.
//
//   loss = (1/ns^2) * sum_ij s_i s_j K(i,j),  s_i = +1 (source) / -1 (target)
//   K(i,j) = sum_{k=0..4} exp(-l2_ij / (bw0 * 2^k)),  l2 = |xi|^2+|xj|^2-2<xi,xj>
//   bw0 = [2n*sum|x|^2 - 2*|colsum|^2] / (n^2-n) / 4      (closed form, no Gram)
//
// Pipeline (all deterministic, no atomics):
//   k1: fp32->bf16 cast to ws, per-row |x|^2, per-block colsum/sqsum partials
//   k2: bandwidth scalar from partials
//   k3: triangular-tiled bf16 MFMA Gram + fused exp epilogue -> per-block partial
//       *** v3: measured post-mortem of v2 (no-LDS): k3=80.7us, MfmaUtil 8%,
//       Occupancy 18.6% -> latency-bound; VGPR=92 proves the register pipeline
//       was collapsed by the compiler. Revert to global_load_lds staging, plus:
//       (a) T3-minimum 2-phase: double-buffered BK=32 LDS (32 KB), prefetch
//           kt+1 issued BEFORE computing kt, manual asm vmcnt(0) + raw
//           s_barrier (avoids __syncthreads' full drain killing overlap);
//       (b) XOR swizzle on the staged layout (audited optimal: 8 lanes per
//           4-bank span = wave64-b128 hardware minimum of 8 cy; note BK=32
//           row-major would also be minimal -- the OLD BK=64 layout was the
//           2x-penalty one).
//       MFMA order unchanged -> numerics identical to the absmax=0.0 run.
//       [Round 6: resubmitted unchanged after 6th infra timeout; audited
//       global_load_lds slot math + C/D epilogue mapping this round.] ***
//   k4: reduce 2080 partials -> loss
// ws usage ~4.5 MB.
// ---------------------------------------------------------------------------

#define NROW 8192
#define NS   4096
#define DD   256
#define TILE 128
#define BK2  32                     // K-step per LDS tile (double-buffered)
#define NTB  64                     // 8192/128 row tiles
#define NBLK (NTB*(NTB+1)/2)        // 2080 triangular blocks
#define K1B  128                    // k1 blocks (64 rows each)

typedef __bf16 bf16_t;
typedef __bf16 bf16x8 __attribute__((ext_vector_type(8)));
typedef __bf16 bf16x4 __attribute__((ext_vector_type(4)));
typedef float  f32x4  __attribute__((ext_vector_type(4)));

// ws byte offsets
#define OFF_CPAR 0                          // float[4]
#define OFF_SQ   1024                       // float[8192]
#define OFF_CS   (OFF_SQ + 8192*4)          // float[K1B*256]
#define OFF_SS   (OFF_CS + K1B*256*4)       // float[K1B]
#define OFF_PART (OFF_SS + 1024)            // float[NBLK]
#define OFF_TBF  (1<<18)                    // bf16[8192*256] = 4 MB

__device__ __forceinline__ void async16(const void* g, void* l) {
  // global -> LDS direct copy, 16 B per lane. LDS dest must be wave-uniform
  // base (+ lane*16 applied by HW). Integer round-trip for the addrspace casts.
  __builtin_amdgcn_global_load_lds(
      (const __attribute__((address_space(1))) void*)(uintptr_t)g,
      (__attribute__((address_space(3))) void*)(uintptr_t)l, 16, 0, 0);
}

// --------------------------- k1: prep ---------------------------------------
__global__ __launch_bounds__(256) void k1_prep(const float* __restrict__ src,
                                               const float* __restrict__ tgt,
                                               float* __restrict__ sq,
                                               float* __restrict__ cs_part,
                                               float* __restrict__ ss_part,
                                               bf16_t* __restrict__ tbf) {
  const int b = blockIdx.x, tid = threadIdx.x;
  const int w = tid >> 6, lane = tid & 63;
  float4 csum = make_float4(0.f, 0.f, 0.f, 0.f);
  float wss = 0.f;
  for (int r = 0; r < 16; ++r) {
    const int row = b * 64 + w * 16 + r;
    const float* rp = (row < NS) ? (src + (size_t)row * DD)
                                 : (tgt + (size_t)(row - NS) * DD);
    float4 v = ((const float4*)rp)[lane];
    bf16x4 o;
    o[0] = (bf16_t)v.x; o[1] = (bf16_t)v.y; o[2] = (bf16_t)v.z; o[3] = (bf16_t)v.w;
    *(bf16x4*)(tbf + (size_t)row * DD + lane * 4) = o;
    float s2 = v.x*v.x + v.y*v.y + v.z*v.z + v.w*v.w;
    #pragma unroll
    for (int off = 32; off >= 1; off >>= 1) s2 += __shfl_xor(s2, off);
    if (lane == 0) { sq[row] = s2; wss += s2; }
    csum.x += v.x; csum.y += v.y; csum.z += v.z; csum.w += v.w;
  }
  __shared__ float cls[4][256];
  __shared__ float sls[4];
  ((float4*)cls[w])[lane] = csum;
  if (lane == 0) sls[w] = wss;
  __syncthreads();
  cs_part[b * 256 + tid] = cls[0][tid] + cls[1][tid] + cls[2][tid] + cls[3][tid];
  if (tid == 0) ss_part[b] = sls[0] + sls[1] + sls[2] + sls[3];
}

// --------------------------- k2: bandwidth -----------------------------------
__global__ __launch_bounds__(256) void k2_bw(const float* __restrict__ cs_part,
                                             const float* __restrict__ ss_part,
                                             float* __restrict__ cpar) {
  const int tid = threadIdx.x, w = tid >> 6, lane = tid & 63;
  float c = 0.f;
  for (int b = 0; b < K1B; ++b) c += cs_part[b * 256 + tid];
  double csq = (double)c * (double)c;
  double ssq = (tid < K1B) ? (double)ss_part[tid] : 0.0;
  #pragma unroll
  for (int off = 32; off >= 1; off >>= 1) {
    csq += __shfl_xor(csq, off);
    ssq += __shfl_xor(ssq, off);
  }
  __shared__ double rc[4], rs[4];
  if (lane == 0) { rc[w] = csq; rs[w] = ssq; }
  __syncthreads();
  if (tid == 0) {
    double C = rc[0] + rc[1] + rc[2] + rc[3];
    double S = rs[0] + rs[1] + rs[2] + rs[3];
    const double n = (double)NROW;
    double suml2 = 2.0 * n * S - 2.0 * C;
    double bw0 = suml2 / (n * n - n) / 4.0;   // / KERNEL_MUL^(KERNEL_NUM//2)
    // v = exp2(-l2 * cE) = exp(-l2/(16*bw0)); kernels = v+v^2+v^4+v^8+v^16
    cpar[0] = (float)(1.4426950408889634 / (16.0 * bw0));
  }
}

// --------------------------- k3: Gram + fused epilogue -----------------------
// 2-phase double-buffered LDS staging with XOR-swizzled layout.
// LDS tile: [128 rows][4 chunks of 16B] per buffer per matrix (8 KB).
// Slot (r, c) holds global chunk (c ^ ((r>>1)&3)) of row r  -> min-cycle banks.

__device__ __forceinline__ void stage(const bf16_t* __restrict__ Ag,
                                      const bf16_t* __restrict__ Bg,
                                      bf16_t* As, bf16_t* Bs,
                                      int kt, int tid, int wbase) {
  #pragma unroll
  for (int it = 0; it < 2; ++it) {
    const int c  = it * 256 + tid;              // chunk slot id, 0..511
    const int r  = c >> 2;                      // row 0..127
    const int sc = (c & 3) ^ ((r >> 1) & 3);    // swizzled source chunk
    const bf16_t* gsrcA = Ag + (size_t)r * DD + kt * BK2 + sc * 8;
    const bf16_t* gsrcB = Bg + (size_t)r * DD + kt * BK2 + sc * 8;
    char* da = (char*)As + (size_t)(it * 256 + wbase) * 16;  // wave-uniform
    char* db = (char*)Bs + (size_t)(it * 256 + wbase) * 16;
    async16(gsrcA, da);
    async16(gsrcB, db);
  }
}

__global__ __launch_bounds__(256) void k3_mmd(const bf16_t* __restrict__ tbf,
                                              const float* __restrict__ sqg,
                                              const float* __restrict__ cpar,
                                              float* __restrict__ part) {
  __shared__ __align__(16) bf16_t As[2][TILE * BK2];   // 2 x 8 KB
  __shared__ __align__(16) bf16_t Bs[2][TILE * BK2];   // 2 x 8 KB
  __shared__ float red[4];

  const int t = blockIdx.x;
  int bi = (int)((sqrtf(8.0f * (float)t + 1.0f) - 1.0f) * 0.5f);
  while ((bi + 1) * (bi + 2) / 2 <= t) ++bi;
  while (bi * (bi + 1) / 2 > t) --bi;
  const int bj = t - bi * (bi + 1) / 2;            // bj <= bi

  const int tid = threadIdx.x;
  const int w = tid >> 6, lane = tid & 63;
  const int m0 = (w >> 1) * 64, n0 = (w & 1) * 64; // wave quadrant in 128x128
  const int wbase = tid & ~63;                     // w*64 (wave-uniform)

  const float cE = cpar[0];

  f32x4 acc[4][4] = {};

  const bf16_t* Ag = tbf + (size_t)bi * TILE * DD;
  const bf16_t* Bg = tbf + (size_t)bj * TILE * DD;

  // Read-side swizzle folds to a per-lane constant element offset:
  // chunk q = lane>>4 XOR s(row) = (lane>>1)&3  (row = 16*a + (lane&15)).
  const int kidx = (((lane >> 4) ^ ((lane >> 1) & 3)) * 8);
  const int lrow = lane & 15;

  // Prologue: stage kt=0, publish.
  stage(Ag, Bg, As[0], Bs[0], 0, tid, wbase);
  asm volatile("s_waitcnt vmcnt(0)" ::: "memory");
  __builtin_amdgcn_s_barrier();
  __builtin_amdgcn_sched_barrier(0);

  #pragma unroll
  for (int kt = 0; kt < 8; ++kt) {                 // K = 256 in BK2=32 steps
    const int cur = kt & 1;
    if (kt < 7)                                    // prefetch next tile first
      stage(Ag, Bg, As[cur ^ 1], Bs[cur ^ 1], kt + 1, tid, wbase);

    bf16x8 af[4], bfr[4];
    #pragma unroll
    for (int mi = 0; mi < 4; ++mi)
      af[mi] = *(const bf16x8*)(As[cur] + (m0 + mi * 16 + lrow) * BK2 + kidx);
    #pragma unroll
    for (int ni = 0; ni < 4; ++ni)
      bfr[ni] = *(const bf16x8*)(Bs[cur] + (n0 + ni * 16 + lrow) * BK2 + kidx);
    #pragma unroll
    for (int mi = 0; mi < 4; ++mi)
      #pragma unroll
      for (int ni = 0; ni < 4; ++ni)
        acc[mi][ni] = __builtin_amdgcn_mfma_f32_16x16x32_bf16(
            af[mi], bfr[ni], acc[mi][ni], 0, 0, 0);

    if (kt < 7) {
      asm volatile("s_waitcnt vmcnt(0)" ::: "memory");  // next tile landed
      __builtin_amdgcn_s_barrier();
      __builtin_amdgcn_sched_barrier(0);
    }
  }

  // Fused epilogue: e = (2g - sqi - sqj)*cE; v = 2^e; K = v+v^2+v^4+v^8+v^16
  const float c2 = 2.0f * cE;
  float bjv[4];
  #pragma unroll
  for (int ni = 0; ni < 4; ++ni)
    bjv[ni] = sqg[bj * TILE + n0 + ni * 16 + lrow] * cE;

  float tsum = 0.f;
  #pragma unroll
  for (int mi = 0; mi < 4; ++mi) {
    float ai[4];
    #pragma unroll
    for (int r = 0; r < 4; ++r)
      ai[r] = sqg[bi * TILE + m0 + mi * 16 + (lane >> 4) * 4 + r] * cE;
    #pragma unroll
    for (int ni = 0; ni < 4; ++ni) {
      #pragma unroll
      for (int r = 0; r < 4; ++r) {
        const float g = acc[mi][ni][r];
        const float e = fmaf(g, c2, -(ai[r] + bjv[ni]));
        const float v   = __builtin_amdgcn_exp2f(e);
        const float v2  = v * v;
        const float v4  = v2 * v2;
        const float v8  = v4 * v4;
        const float v16 = v8 * v8;
        tsum += v + v2 + v4 + v8 + v16;
      }
    }
  }
  #pragma unroll
  for (int off = 32; off >= 1; off >>= 1) tsum += __shfl_xor(tsum, off);
  if (lane == 0) red[w] = tsum;
  __syncthreads();
  if (tid == 0) {
    const float s    = red[0] + red[1] + red[2] + red[3];
    const float sign = ((bi < NS / TILE) == (bj < NS / TILE)) ? 1.f : -1.f;
    const float wt   = (bi == bj) ? 1.f : 2.f;     // off-diag tiles counted twice
    part[t] = s * sign * wt;
  }
}

// --------------------------- k4: finalize ------------------------------------
__global__ __launch_bounds__(256) void k4_fin(const float* __restrict__ part,
                                              float* __restrict__ out) {
  const int tid = threadIdx.x, w = tid >> 6, lane = tid & 63;
  double s = 0.0;
  for (int i = tid; i < NBLK; i += 256) s += (double)part[i];
  #pragma unroll
  for (int off = 32; off >= 1; off >>= 1) s += __shfl_xor(s, off);
  __shared__ double rd[4];
  if (lane == 0) rd[w] = s;
  __syncthreads();
  if (tid == 0)
    out[0] = (float)((rd[0] + rd[1] + rd[2] + rd[3]) /
                     ((double)NS * (double)NS));
}

// --------------------------- launch ------------------------------------------
extern "C" void kernel_launch(void* const* d_in, const int* in_sizes, int n_in,
                              void* d_out, int out_size, void* d_ws, size_t ws_size,
                              hipStream_t stream) {
  const float* src = (const float*)d_in[0];
  const float* tgt = (const float*)d_in[1];
  char* ws = (char*)d_ws;
  float*  cpar = (float*)(ws + OFF_CPAR);
  float*  sq   = (float*)(ws + OFF_SQ);
  float*  csp  = (float*)(ws + OFF_CS);
  float*  ssp  = (float*)(ws + OFF_SS);
  float*  part = (float*)(ws + OFF_PART);
  bf16_t* tbf  = (bf16_t*)(ws + OFF_TBF);

  k1_prep<<<K1B, 256, 0, stream>>>(src, tgt, sq, csp, ssp, tbf);
  k2_bw  <<<1,   256, 0, stream>>>(csp, ssp, cpar);
  k3_mmd <<<NBLK,256, 0, stream>>>(tbf, sq, cpar, part);
  k4_fin <<<1,   256, 0, stream>>>(part, (float*)d_out);
}

// Round 11
// 104.724 us; speedup vs baseline: 1.4692x; 1.0445x over previous
//
#include <hip/hip_runtime.h>
#include <hip/hip_bf16.h>
#include <stdint.h>

// ---------------------------------------------------------------------------
// MMD loss, N=4096 source + 4096 target rows, D=256, fp32 in, fp32 scalar out.
//
//   loss = (1/ns^2) * sum_ij s_i s_j K(i,j),  s_i = +1 (source) / -1 (target)
//   K(i,j) = sum_{k=0..4} exp(-l2_ij / (bw0 * 2^k)),  l2 = |xi|^2+|xj|^2-2<xi,xj>
//   bw0 = [2n*sum|x|^2 - 2*|colsum|^2] / (n^2-n) / 4      (closed form, no Gram)
//
// Pipeline (all deterministic, no atomics):
//   k1: fp32->bf16 cast to ws, per-row |x|^2, per-block colsum/sqsum partials
//   k2: bandwidth scalar from partials
//   k3: triangular-tiled bf16 MFMA Gram + fused exp epilogue -> per-block partial
//       *** v4: session decomposition: total = fill(43, harness) + fixed(~30)
//       + k3. v3's k3 = ~36us (2-buffer, in-loop vmcnt(0) drain) ~= baseline's
//       34.9. Work floor ~15us; the shared ~20us stall is the per-kt FULL
//       vmcnt(0) drain exposing L2 latency at every barrier (T4 lesson:
//       never drain to 0 in the main loop). v4: 3-buffer rotation with
//       counted vmcnt(4) -- stage(kt+2) issued at top of iter kt, trailing
//       wait only requires stage(kt+1) landed; stage(kt+2)'s 4 loads stay in
//       flight ACROSS the barrier. Hazard-audited: buf[(kt+2)%3]'s previous
//       readers completed ds_reads before iter kt-1's trailing barrier.
//       MFMA order unchanged -> numerics identical (absmax was 0.0).
//       [Round 10: resubmitted unchanged after 9th infra timeout; audited
//       triangular-index fp32 exactness + occupancy ceiling (3 blk/CU LDS-
//       bound vs v3's 4 -- the quantified risk, covered by decision rule c).]
//   k4: reduce 2080 partials -> loss
// ws usage ~4.5 MB.
// ---------------------------------------------------------------------------

#define NROW 8192
#define NS   4096
#define DD   256
#define TILE 128
#define BK2  32                     // K-step per LDS tile (triple-buffered)
#define NTB  64                     // 8192/128 row tiles
#define NBLK (NTB*(NTB+1)/2)        // 2080 triangular blocks
#define K1B  128                    // k1 blocks (64 rows each)

typedef __bf16 bf16_t;
typedef __bf16 bf16x8 __attribute__((ext_vector_type(8)));
typedef __bf16 bf16x4 __attribute__((ext_vector_type(4)));
typedef float  f32x4  __attribute__((ext_vector_type(4)));

// ws byte offsets
#define OFF_CPAR 0                          // float[4]
#define OFF_SQ   1024                       // float[8192]
#define OFF_CS   (OFF_SQ + 8192*4)          // float[K1B*256]
#define OFF_SS   (OFF_CS + K1B*256*4)       // float[K1B]
#define OFF_PART (OFF_SS + 1024)            // float[NBLK]
#define OFF_TBF  (1<<18)                    // bf16[8192*256] = 4 MB

__device__ __forceinline__ void async16(const void* g, void* l) {
  // global -> LDS direct copy, 16 B per lane. LDS dest must be wave-uniform
  // base (+ lane*16 applied by HW). Integer round-trip for the addrspace casts.
  __builtin_amdgcn_global_load_lds(
      (const __attribute__((address_space(1))) void*)(uintptr_t)g,
      (__attribute__((address_space(3))) void*)(uintptr_t)l, 16, 0, 0);
}

// --------------------------- k1: prep ---------------------------------------
__global__ __launch_bounds__(256) void k1_prep(const float* __restrict__ src,
                                               const float* __restrict__ tgt,
                                               float* __restrict__ sq,
                                               float* __restrict__ cs_part,
                                               float* __restrict__ ss_part,
                                               bf16_t* __restrict__ tbf) {
  const int b = blockIdx.x, tid = threadIdx.x;
  const int w = tid >> 6, lane = tid & 63;
  float4 csum = make_float4(0.f, 0.f, 0.f, 0.f);
  float wss = 0.f;
  for (int r = 0; r < 16; ++r) {
    const int row = b * 64 + w * 16 + r;
    const float* rp = (row < NS) ? (src + (size_t)row * DD)
                                 : (tgt + (size_t)(row - NS) * DD);
    float4 v = ((const float4*)rp)[lane];
    bf16x4 o;
    o[0] = (bf16_t)v.x; o[1] = (bf16_t)v.y; o[2] = (bf16_t)v.z; o[3] = (bf16_t)v.w;
    *(bf16x4*)(tbf + (size_t)row * DD + lane * 4) = o;
    float s2 = v.x*v.x + v.y*v.y + v.z*v.z + v.w*v.w;
    #pragma unroll
    for (int off = 32; off >= 1; off >>= 1) s2 += __shfl_xor(s2, off);
    if (lane == 0) { sq[row] = s2; wss += s2; }
    csum.x += v.x; csum.y += v.y; csum.z += v.z; csum.w += v.w;
  }
  __shared__ float cls[4][256];
  __shared__ float sls[4];
  ((float4*)cls[w])[lane] = csum;
  if (lane == 0) sls[w] = wss;
  __syncthreads();
  cs_part[b * 256 + tid] = cls[0][tid] + cls[1][tid] + cls[2][tid] + cls[3][tid];
  if (tid == 0) ss_part[b] = sls[0] + sls[1] + sls[2] + sls[3];
}

// --------------------------- k2: bandwidth -----------------------------------
__global__ __launch_bounds__(256) void k2_bw(const float* __restrict__ cs_part,
                                             const float* __restrict__ ss_part,
                                             float* __restrict__ cpar) {
  const int tid = threadIdx.x, w = tid >> 6, lane = tid & 63;
  float c = 0.f;
  for (int b = 0; b < K1B; ++b) c += cs_part[b * 256 + tid];
  double csq = (double)c * (double)c;
  double ssq = (tid < K1B) ? (double)ss_part[tid] : 0.0;
  #pragma unroll
  for (int off = 32; off >= 1; off >>= 1) {
    csq += __shfl_xor(csq, off);
    ssq += __shfl_xor(ssq, off);
  }
  __shared__ double rc[4], rs[4];
  if (lane == 0) { rc[w] = csq; rs[w] = ssq; }
  __syncthreads();
  if (tid == 0) {
    double C = rc[0] + rc[1] + rc[2] + rc[3];
    double S = rs[0] + rs[1] + rs[2] + rs[3];
    const double n = (double)NROW;
    double suml2 = 2.0 * n * S - 2.0 * C;
    double bw0 = suml2 / (n * n - n) / 4.0;   // / KERNEL_MUL^(KERNEL_NUM//2)
    // v = exp2(-l2 * cE) = exp(-l2/(16*bw0)); kernels = v+v^2+v^4+v^8+v^16
    cpar[0] = (float)(1.4426950408889634 / (16.0 * bw0));
  }
}

// --------------------------- k3: Gram + fused epilogue -----------------------
// 3-buffer rotation, counted vmcnt: stage(kt+2) issued at top of iter kt;
// trailing wait vmcnt(4) only requires stage(kt+1)'s 4 loads done, leaving
// stage(kt+2) in flight across the barrier (T4: never drain to 0 in-loop).
// LDS tile: [128 rows][4 chunks of 16B] per buffer per matrix (8 KB).
// Slot (r, c) holds global chunk (c ^ ((r>>1)&3)) of row r  -> min-cycle banks.

__device__ __forceinline__ void stage(const bf16_t* __restrict__ Ag,
                                      const bf16_t* __restrict__ Bg,
                                      bf16_t* As, bf16_t* Bs,
                                      int kt, int tid, int wbase) {
  #pragma unroll
  for (int it = 0; it < 2; ++it) {
    const int c  = it * 256 + tid;              // chunk slot id, 0..511
    const int r  = c >> 2;                      // row 0..127
    const int sc = (c & 3) ^ ((r >> 1) & 3);    // swizzled source chunk
    const bf16_t* gsrcA = Ag + (size_t)r * DD + kt * BK2 + sc * 8;
    const bf16_t* gsrcB = Bg + (size_t)r * DD + kt * BK2 + sc * 8;
    char* da = (char*)As + (size_t)(it * 256 + wbase) * 16;  // wave-uniform
    char* db = (char*)Bs + (size_t)(it * 256 + wbase) * 16;
    async16(gsrcA, da);
    async16(gsrcB, db);
  }
}

__global__ __launch_bounds__(256) void k3_mmd(const bf16_t* __restrict__ tbf,
                                              const float* __restrict__ sqg,
                                              const float* __restrict__ cpar,
                                              float* __restrict__ part) {
  __shared__ __align__(16) bf16_t As[3][TILE * BK2];   // 3 x 8 KB
  __shared__ __align__(16) bf16_t Bs[3][TILE * BK2];   // 3 x 8 KB
  __shared__ float red[4];

  const int t = blockIdx.x;
  int bi = (int)((sqrtf(8.0f * (float)t + 1.0f) - 1.0f) * 0.5f);
  while ((bi + 1) * (bi + 2) / 2 <= t) ++bi;
  while (bi * (bi + 1) / 2 > t) --bi;
  const int bj = t - bi * (bi + 1) / 2;            // bj <= bi

  const int tid = threadIdx.x;
  const int w = tid >> 6, lane = tid & 63;
  const int m0 = (w >> 1) * 64, n0 = (w & 1) * 64; // wave quadrant in 128x128
  const int wbase = tid & ~63;                     // w*64 (wave-uniform)

  const float cE = cpar[0];

  f32x4 acc[4][4] = {};

  const bf16_t* Ag = tbf + (size_t)bi * TILE * DD;
  const bf16_t* Bg = tbf + (size_t)bj * TILE * DD;

  // Read-side swizzle folds to a per-lane constant element offset:
  // chunk q = lane>>4 XOR s(row) = (lane>>1)&3  (row = 16*a + (lane&15)).
  const int kidx = (((lane >> 4) ^ ((lane >> 1) & 3)) * 8);
  const int lrow = lane & 15;

  // Prologue: stage kt=0 and kt=1; publish buffer 0 (its 4 loads are the
  // oldest of the 8 outstanding -> vmcnt(4)).
  stage(Ag, Bg, As[0], Bs[0], 0, tid, wbase);
  stage(Ag, Bg, As[1], Bs[1], 1, tid, wbase);
  asm volatile("s_waitcnt vmcnt(4)" ::: "memory");
  __builtin_amdgcn_s_barrier();
  __builtin_amdgcn_sched_barrier(0);

  #pragma unroll
  for (int kt = 0; kt < 8; ++kt) {                 // K = 256 in BK2=32 steps
    if (kt < 6)                                    // keep 2 stages in flight
      stage(Ag, Bg, As[(kt + 2) % 3], Bs[(kt + 2) % 3], kt + 2, tid, wbase);

    const int cur = kt % 3;
    bf16x8 af[4], bfr[4];
    #pragma unroll
    for (int mi = 0; mi < 4; ++mi)
      af[mi] = *(const bf16x8*)(As[cur] + (m0 + mi * 16 + lrow) * BK2 + kidx);
    #pragma unroll
    for (int ni = 0; ni < 4; ++ni)
      bfr[ni] = *(const bf16x8*)(Bs[cur] + (n0 + ni * 16 + lrow) * BK2 + kidx);
    #pragma unroll
    for (int mi = 0; mi < 4; ++mi)
      #pragma unroll
      for (int ni = 0; ni < 4; ++ni)
        acc[mi][ni] = __builtin_amdgcn_mfma_f32_16x16x32_bf16(
            af[mi], bfr[ni], acc[mi][ni], 0, 0, 0);

    if (kt < 7) {
      // Wait only for stage(kt+1): at kt<6, stage(kt+2)'s 4 loads are the
      // newest and may stay outstanding -> vmcnt(4). At kt==6 nothing was
      // issued this iter, so stage(7) is the only one left -> vmcnt(0).
      if (kt < 6) { asm volatile("s_waitcnt vmcnt(4)" ::: "memory"); }
      else       { asm volatile("s_waitcnt vmcnt(0)" ::: "memory"); }
      __builtin_amdgcn_s_barrier();
      __builtin_amdgcn_sched_barrier(0);
    }
  }

  // Fused epilogue: e = (2g - sqi - sqj)*cE; v = 2^e; K = v+v^2+v^4+v^8+v^16
  const float c2 = 2.0f * cE;
  float bjv[4];
  #pragma unroll
  for (int ni = 0; ni < 4; ++ni)
    bjv[ni] = sqg[bj * TILE + n0 + ni * 16 + lrow] * cE;

  float tsum = 0.f;
  #pragma unroll
  for (int mi = 0; mi < 4; ++mi) {
    float ai[4];
    #pragma unroll
    for (int r = 0; r < 4; ++r)
      ai[r] = sqg[bi * TILE + m0 + mi * 16 + (lane >> 4) * 4 + r] * cE;
    #pragma unroll
    for (int ni = 0; ni < 4; ++ni) {
      #pragma unroll
      for (int r = 0; r < 4; ++r) {
        const float g = acc[mi][ni][r];
        const float e = fmaf(g, c2, -(ai[r] + bjv[ni]));
        const float v   = __builtin_amdgcn_exp2f(e);
        const float v2  = v * v;
        const float v4  = v2 * v2;
        const float v8  = v4 * v4;
        const float v16 = v8 * v8;
        tsum += v + v2 + v4 + v8 + v16;
      }
    }
  }
  #pragma unroll
  for (int off = 32; off >= 1; off >>= 1) tsum += __shfl_xor(tsum, off);
  if (lane == 0) red[w] = tsum;
  __syncthreads();
  if (tid == 0) {
    const float s    = red[0] + red[1] + red[2] + red[3];
    const float sign = ((bi < NS / TILE) == (bj < NS / TILE)) ? 1.f : -1.f;
    const float wt   = (bi == bj) ? 1.f : 2.f;     // off-diag tiles counted twice
    part[t] = s * sign * wt;
  }
}

// --------------------------- k4: finalize ------------------------------------
__global__ __launch_bounds__(256) void k4_fin(const float* __restrict__ part,
                                              float* __restrict__ out) {
  const int tid = threadIdx.x, w = tid >> 6, lane = tid & 63;
  double s = 0.0;
  for (int i = tid; i < NBLK; i += 256) s += (double)part[i];
  #pragma unroll
  for (int off = 32; off >= 1; off >>= 1) s += __shfl_xor(s, off);
  __shared__ double rd[4];
  if (lane == 0) rd[w] = s;
  __syncthreads();
  if (tid == 0)
    out[0] = (float)((rd[0] + rd[1] + rd[2] + rd[3]) /
                     ((double)NS * (double)NS));
}

// --------------------------- launch ------------------------------------------
extern "C" void kernel_launch(void* const* d_in, const int* in_sizes, int n_in,
                              void* d_out, int out_size, void* d_ws, size_t ws_size,
                              hipStream_t stream) {
  const float* src = (const float*)d_in[0];
  const float* tgt = (const float*)d_in[1];
  char* ws = (char*)d_ws;
  float*  cpar = (float*)(ws + OFF_CPAR);
  float*  sq   = (float*)(ws + OFF_SQ);
  float*  csp  = (float*)(ws + OFF_CS);
  float*  ssp  = (float*)(ws + OFF_SS);
  float*  part = (float*)(ws + OFF_PART);
  bf16_t* tbf  = (bf16_t*)(ws + OFF_TBF);

  k1_prep<<<K1B, 256, 0, stream>>>(src, tgt, sq, csp, ssp, tbf);
  k2_bw  <<<1,   256, 0, stream>>>(csp, ssp, cpar);
  k3_mmd <<<NBLK,256, 0, stream>>>(tbf, sq, cpar, part);
  k4_fin <<<1,   256, 0, stream>>>(part, (float*)d_out);
}